// Round 2
// baseline (805.136 us; speedup 1.0000x reference)
//
#include <hip/hip_runtime.h>
#include <hip/hip_bf16.h>
#include <stdint.h>

// ---------------------------------------------------------------------------
// Transformer block, B=4 S=2048 E=2048 H=1.
// H=1 -> softmax over a size-1 axis == 1.0 -> attn_out = x @ w_kv + b_kv.
// w_attn / b_attn / mask are dead inputs.
// Pipeline: t1 = x + (x@w_kv + b_kv); h = LN1(t1);
//           g = gelu(h@w_fc + b_fc);  t2 = x + (g@w_mproj + b_mproj);
//           out = LN2(t2).
// GEMMs: bf16 MFMA (fp32 accum), m97 structure. t1/t2 live in d_out (64 MiB).
// Workspace layout adapts to ws_size (>=224MiB full, else 4-way M-chunked
// GEMM2/3 needing 128 MiB) -- round-1 crash was ws overflow (328 MiB used,
// never checked ws_size).
// ---------------------------------------------------------------------------

typedef __attribute__((ext_vector_type(4))) float f32x4;
typedef __attribute__((ext_vector_type(8))) __bf16 bf16x8;
typedef __attribute__((ext_vector_type(8))) unsigned short ushort8;

__device__ __forceinline__ unsigned short f2bf(float f) {
  unsigned int u = __float_as_uint(f);
  return (unsigned short)((u + 0x7FFFu + ((u >> 16) & 1u)) >> 16);  // RNE
}

// async global->LDS, 16B per lane. LDS dest is wave-uniform base; HW writes
// base + lane*16. Global src per-lane. Low-32 of a generic LDS pointer is the
// LDS offset on gfx9+ (aperture check uses upper 32 bits).
__device__ __forceinline__ void gload_lds16(const void* g, void* l) {
  __builtin_amdgcn_global_load_lds(
      (const __attribute__((address_space(1))) unsigned int*)(uintptr_t)g,
      (__attribute__((address_space(3))) unsigned int*)(unsigned int)(uintptr_t)l,
      16, 0, 0);
}

// ---------------------------------------------------------------------------
// f32 -> bf16 convert (2x float4 in, 1x ushort8 out per thread)
// ---------------------------------------------------------------------------
__global__ __launch_bounds__(256) void cvt_bf16_kernel(
    const float* __restrict__ in, unsigned short* __restrict__ out, int n8) {
  int i = blockIdx.x * 256 + threadIdx.x;
  if (i >= n8) return;
  const size_t base = (size_t)i * 8;
  float4 a = *(const float4*)(in + base);
  float4 b = *(const float4*)(in + base + 4);
  ushort8 o;
  o[0] = f2bf(a.x); o[1] = f2bf(a.y); o[2] = f2bf(a.z); o[3] = f2bf(a.w);
  o[4] = f2bf(b.x); o[5] = f2bf(b.y); o[6] = f2bf(b.z); o[7] = f2bf(b.w);
  *(ushort8*)(out + base) = o;
}

// ---------------------------------------------------------------------------
// Transpose + convert: W (R x C, f32 row-major) -> WT (C x R, bf16 row-major)
// ---------------------------------------------------------------------------
__global__ __launch_bounds__(256) void transpose_cvt(
    const float* __restrict__ W, unsigned short* __restrict__ WT, int R, int C) {
  __shared__ unsigned short t[64][66];
  const int c0 = blockIdx.x * 64, r0 = blockIdx.y * 64;
  const int tid = threadIdx.x;
  const int lr = tid >> 4;         // 0..15
  const int lc = (tid & 15) * 4;   // 0..60
#pragma unroll
  for (int p = 0; p < 4; ++p) {
    const int r = lr + p * 16;
    float4 v = *(const float4*)(W + (size_t)(r0 + r) * C + c0 + lc);
    t[r][lc + 0] = f2bf(v.x);
    t[r][lc + 1] = f2bf(v.y);
    t[r][lc + 2] = f2bf(v.z);
    t[r][lc + 3] = f2bf(v.w);
  }
  __syncthreads();
#pragma unroll
  for (int p = 0; p < 4; ++p) {
    const int oc = lr + p * 16;
    ushort4 o;
    o.x = t[lc + 0][oc];
    o.y = t[lc + 1][oc];
    o.z = t[lc + 2][oc];
    o.w = t[lc + 3][oc];
    *(ushort4*)(WT + (size_t)(c0 + oc) * R + r0 + lc) = o;
  }
}

// ---------------------------------------------------------------------------
// bf16 GEMM, m97 structure: 128x128 tile, BK=64, 4 waves (2x2), 4x4 16x16x32
// MFMA fragments per wave. global_load_lds staging, XOR chunk swizzle
// (pre-swizzled GLOBAL source, linear LDS dest; ds_read applies same XOR).
// EPI 0: out_f32[idx] = acc + bias[col] + xres[idx]
// EPI 1: out_bf16[idx] = gelu_exact(acc + bias[col])
// ---------------------------------------------------------------------------
#define BM 128
#define BN 128
#define BK 64

template <int EPI>
__global__ __launch_bounds__(256, 3) void gemm_bf16(
    const unsigned short* __restrict__ A,   // M x K bf16
    const unsigned short* __restrict__ BT,  // N x K bf16
    const float* __restrict__ bias,         // N
    const float* __restrict__ xres,         // M x N f32 (EPI==0)
    void* __restrict__ out, int N, int K) {
  __shared__ alignas(16) unsigned short smA[BM * BK];
  __shared__ alignas(16) unsigned short smB[BN * BK];

  const int tid = threadIdx.x;
  const int lane = tid & 63;
  const int w = tid >> 6;
  const int wr = w >> 1, wc = w & 1;

  // XCD-bijective swizzle (all grids are multiples of 8)
  const int nbn = N / BN;
  const int nwg = gridDim.x;
  const int bid = blockIdx.x;
  const int wg = (bid & 7) * (nwg >> 3) + (bid >> 3);
  const int bm = wg / nbn, bn = wg % nbn;

  // staging: issue i covers tile rows w*32+i*8 .. +7; lane l -> row +(l>>3),
  // physical chunk l&7 holds logical chunk (l&7)^(row&7).
  const int srow = (w << 5) + (lane >> 3);
  const int sc = (lane & 7) ^ ((lane >> 3) & 7);
  const unsigned short* gA = A + (size_t)(bm * BM + srow) * K + sc * 8;
  const unsigned short* gB = BT + (size_t)(bn * BN + srow) * K + sc * 8;
  unsigned short* lA = smA + (w << 5) * BK;
  unsigned short* lB = smB + (w << 5) * BK;

  const int arow = (wr << 6) + (lane & 15);
  const int brow = (wc << 6) + (lane & 15);
  const int kg = lane >> 4;
  const int r7 = lane & 7;  // == read-row & 7

  f32x4 acc[4][4] = {};

  const int nkt = K / BK;
  for (int kt = 0; kt < nkt; ++kt) {
    const size_t koff = (size_t)kt * BK;
#pragma unroll
    for (int i = 0; i < 4; ++i) {
      gload_lds16(gA + (size_t)(i * 8) * K + koff, lA + i * 8 * BK);
      gload_lds16(gB + (size_t)(i * 8) * K + koff, lB + i * 8 * BK);
    }
    __syncthreads();  // drains vmcnt(0): staged tile visible
#pragma unroll
    for (int kk = 0; kk < 2; ++kk) {
      bf16x8 af[4], bfr[4];
#pragma unroll
      for (int m = 0; m < 4; ++m) {
        const int off = (arow + m * 16) * (BK * 2) + ((((kk << 2) + kg) ^ r7) << 4);
        af[m] = *reinterpret_cast<const bf16x8*>((const char*)smA + off);
      }
#pragma unroll
      for (int n = 0; n < 4; ++n) {
        const int off = (brow + n * 16) * (BK * 2) + ((((kk << 2) + kg) ^ r7) << 4);
        bfr[n] = *reinterpret_cast<const bf16x8*>((const char*)smB + off);
      }
#pragma unroll
      for (int m = 0; m < 4; ++m)
#pragma unroll
        for (int n = 0; n < 4; ++n)
          acc[m][n] = __builtin_amdgcn_mfma_f32_16x16x32_bf16(
              af[m], bfr[n], acc[m][n], 0, 0, 0);
    }
    __syncthreads();
  }

  // epilogue: C/D layout col = lane&15, row = (lane>>4)*4 + reg (m89).
  const int col0 = bn * BN + (wc << 6) + (lane & 15);
  const int row0 = bm * BM + (wr << 6) + ((lane >> 4) << 2);
  float bv[4];
#pragma unroll
  for (int n = 0; n < 4; ++n) bv[n] = bias[col0 + n * 16];
#pragma unroll
  for (int m = 0; m < 4; ++m) {
#pragma unroll
    for (int j = 0; j < 4; ++j) {
      const size_t row = (size_t)(row0 + m * 16 + j);
#pragma unroll
      for (int n = 0; n < 4; ++n) {
        const size_t idx = row * N + col0 + n * 16;
        float v = acc[m][n][j] + bv[n];
        if (EPI == 0) {
          ((float*)out)[idx] = v + xres[idx];
        } else {
          float ge = 0.5f * v * (1.0f + erff(v * 0.7071067811865475f));
          ((unsigned short*)out)[idx] = f2bf(ge);
        }
      }
    }
  }
}

// ---------------------------------------------------------------------------
// Row LayerNorm over E=2048: one block per row, 8 elems/thread.
// ---------------------------------------------------------------------------
template <int OUT_BF16>
__global__ __launch_bounds__(256) void ln_row(const float* __restrict__ tin,
                                              const float* __restrict__ gw,
                                              const float* __restrict__ bw,
                                              void* __restrict__ outp) {
  const int row = blockIdx.x;
  const int tid = threadIdx.x;
  const size_t base = (size_t)row * 2048 + tid * 8;
  alignas(16) float v[8];
  *(float4*)(v) = *(const float4*)(tin + base);
  *(float4*)(v + 4) = *(const float4*)(tin + base + 4);
  float s = 0.f, q = 0.f;
#pragma unroll
  for (int i = 0; i < 8; ++i) { s += v[i]; q += v[i] * v[i]; }
#pragma unroll
  for (int m = 32; m >= 1; m >>= 1) {
    s += __shfl_xor(s, m);
    q += __shfl_xor(q, m);
  }
  __shared__ float red[8];
  if ((tid & 63) == 0) {
    red[tid >> 6] = s;
    red[4 + (tid >> 6)] = q;
  }
  __syncthreads();
  s = red[0] + red[1] + red[2] + red[3];
  q = red[4] + red[5] + red[6] + red[7];
  const float mean = s * (1.0f / 2048.0f);
  float var = q * (1.0f / 2048.0f) - mean * mean;
  var = fmaxf(var, 0.0f);
  const float rstd = rsqrtf(var + 1e-5f);
  alignas(16) float gv[8], bv[8];
  *(float4*)(gv) = *(const float4*)(gw + (size_t)tid * 8);
  *(float4*)(gv + 4) = *(const float4*)(gw + (size_t)tid * 8 + 4);
  *(float4*)(bv) = *(const float4*)(bw + (size_t)tid * 8);
  *(float4*)(bv + 4) = *(const float4*)(bw + (size_t)tid * 8 + 4);
  if (OUT_BF16) {
    ushort8 o;
#pragma unroll
    for (int i = 0; i < 8; ++i)
      o[i] = f2bf((v[i] - mean) * rstd * gv[i] + bv[i]);
    *(ushort8*)((unsigned short*)outp + base) = o;
  } else {
    alignas(16) float r[8];
#pragma unroll
    for (int i = 0; i < 8; ++i) r[i] = (v[i] - mean) * rstd * gv[i] + bv[i];
    *(float4*)((float*)outp + base) = *(float4*)(r);
    *(float4*)((float*)outp + base + 4) = *(float4*)(r + 4);
  }
}

// ---------------------------------------------------------------------------
// Launcher — workspace-size-adaptive (deterministic: ws_size fixed per run).
// ---------------------------------------------------------------------------
extern "C" void kernel_launch(void* const* d_in, const int* in_sizes, int n_in,
                              void* d_out, int out_size, void* d_ws,
                              size_t ws_size, hipStream_t stream) {
  constexpr int M = 8192;  // B*S
  constexpr int E = 2048;
  constexpr int F = 8192;  // 4*E
  const size_t MiB = 1ull << 20;

  const float* x = (const float*)d_in[0];
  // d_in[1] mask, d_in[2] w_attn, d_in[3] b_attn: dead
  const float* w_kv = (const float*)d_in[4];
  const float* b_kv = (const float*)d_in[5];
  const float* ln1_g = (const float*)d_in[6];
  const float* ln1_b = (const float*)d_in[7];
  const float* w_fc = (const float*)d_in[8];
  const float* b_fc = (const float*)d_in[9];
  const float* w_mproj = (const float*)d_in[10];
  const float* b_mproj = (const float*)d_in[11];
  const float* ln2_g = (const float*)d_in[12];
  const float* ln2_b = (const float*)d_in[13];
  float* out = (float*)d_out;
  char* ws = (char*)d_ws;

  // t1/t2 buffer lives in d_out (M*E f32 == out_size). In-place LN2 is safe.
  float* tbuf = out;

  int nch;
  unsigned short *xb, *wkvT, *wfcT, *wmpT, *hb, *gch;
  if (ws_size >= 224 * MiB) {
    // Full path. gb region [0,128Mi); xb(32Mi)@0 and wkvT(8Mi)@32Mi alias it
    // (both dead before GEMM2 writes gb).
    nch = 1;
    gch = (unsigned short*)(ws + 0);
    xb = (unsigned short*)(ws + 0);
    wkvT = (unsigned short*)(ws + 32 * MiB);
    wfcT = (unsigned short*)(ws + 128 * MiB);
    wmpT = (unsigned short*)(ws + 160 * MiB);
    hb = (unsigned short*)(ws + 192 * MiB);
  } else {
    // Compact path: 4-way M-chunked GEMM2/3, 128 MiB total.
    // [0,32): xb then g_chunk; [32,64): wkvT then hb; [64,96): wfcT; [96,128): wmpT.
    nch = 4;
    xb = (unsigned short*)(ws + 0);
    gch = (unsigned short*)(ws + 0);
    wkvT = (unsigned short*)(ws + 32 * MiB);
    hb = (unsigned short*)(ws + 32 * MiB);
    wfcT = (unsigned short*)(ws + 64 * MiB);
    wmpT = (unsigned short*)(ws + 96 * MiB);
  }

  // 1) x -> bf16
  cvt_bf16_kernel<<<(M * E / 8 + 255) / 256, 256, 0, stream>>>(x, xb, M * E / 8);
  // 2) weights -> bf16 transposed (N x K)
  transpose_cvt<<<dim3(E / 64, E / 64), 256, 0, stream>>>(w_kv, wkvT, E, E);
  transpose_cvt<<<dim3(F / 64, E / 64), 256, 0, stream>>>(w_fc, wfcT, E, F);
  transpose_cvt<<<dim3(E / 64, F / 64), 256, 0, stream>>>(w_mproj, wmpT, F, E);
  // 3) t1 = x @ w_kv + b_kv + x   (f32, into d_out)
  gemm_bf16<0><<<(M / BM) * (E / BN), 256, 0, stream>>>(xb, wkvT, b_kv, x, tbuf,
                                                        E, E);
  // 4) h = LN1(t1) -> bf16
  ln_row<1><<<M, 256, 0, stream>>>(tbuf, ln1_g, ln1_b, hb);
  // 5/6) chunked: g = gelu(h @ w_fc + b_fc); t2 = x + g @ w_mproj + b_mproj
  const int Mc = M / nch;
  for (int c = 0; c < nch; ++c) {
    const size_t roff = (size_t)c * Mc;
    gemm_bf16<1><<<(Mc / BM) * (F / BN), 256, 0, stream>>>(
        hb + roff * E, wfcT, b_fc, nullptr, gch, F, E);
    gemm_bf16<0><<<(Mc / BM) * (E / BN), 256, 0, stream>>>(
        gch, wmpT, b_mproj, x + roff * E, tbuf + roff * E, E, F);
  }
  // 7) out = LN2(t2) in place
  ln_row<0><<<M, 256, 0, stream>>>(tbuf, ln2_g, ln2_b, out);
}

// Round 3
// 706.325 us; speedup vs baseline: 1.1399x; 1.1399x over previous
//
#include <hip/hip_runtime.h>
#include <hip/hip_bf16.h>
#include <stdint.h>

// ---------------------------------------------------------------------------
// Transformer block, B=4 S=2048 E=2048 H=1.
// H=1 -> softmax over size-1 axis == 1.0 -> attn_out = x @ w_kv + b_kv.
// Pipeline: t1 = x + (x@w_kv + b_kv); h = LN1(t1);
//           g = gelu(h@w_fc + b_fc);  t2 = x + (g@w_mproj + b_mproj);
//           out = LN2(t2).
// GEMMs: 256x256-tile 8-phase bf16 MFMA kernel (T3+T4+T5), 8 waves, BK=64,
// 128KB LDS dbuf, counted vmcnt(6), raw s_barrier, setprio around MFMA.
// Race-free by construction: each in-place stage targets a region whose last
// ds_read retired a full barrier earlier (quadrant order (0,0),(1,0),(1,1),
// (0,1); stage stream Bhi(t+1)@ph1->other buf, Alo(t+2)@ph3, Ahi+Blo(t+2)@ph4).
// ---------------------------------------------------------------------------

typedef __attribute__((ext_vector_type(4))) float f32x4;
typedef __attribute__((ext_vector_type(8))) __bf16 bf16x8;
typedef __attribute__((ext_vector_type(8))) unsigned short ushort8;

__device__ __forceinline__ unsigned short f2bf(float f) {
  unsigned int u = __float_as_uint(f);
  return (unsigned short)((u + 0x7FFFu + ((u >> 16) & 1u)) >> 16);  // RNE
}

__device__ __forceinline__ void gload_lds16(const void* g, void* l) {
  __builtin_amdgcn_global_load_lds(
      (const __attribute__((address_space(1))) unsigned int*)(uintptr_t)g,
      (__attribute__((address_space(3))) unsigned int*)(unsigned int)(uintptr_t)l,
      16, 0, 0);
}

// ---------------------------------------------------------------------------
// f32 -> bf16 convert
// ---------------------------------------------------------------------------
__global__ __launch_bounds__(256) void cvt_bf16_kernel(
    const float* __restrict__ in, unsigned short* __restrict__ out, int n8) {
  int i = blockIdx.x * 256 + threadIdx.x;
  if (i >= n8) return;
  const size_t base = (size_t)i * 8;
  float4 a = *(const float4*)(in + base);
  float4 b = *(const float4*)(in + base + 4);
  ushort8 o;
  o[0] = f2bf(a.x); o[1] = f2bf(a.y); o[2] = f2bf(a.z); o[3] = f2bf(a.w);
  o[4] = f2bf(b.x); o[5] = f2bf(b.y); o[6] = f2bf(b.z); o[7] = f2bf(b.w);
  *(ushort8*)(out + base) = o;
}

// ---------------------------------------------------------------------------
// Transpose + convert: W (R x C f32) -> WT (C x R bf16)
// ---------------------------------------------------------------------------
__global__ __launch_bounds__(256) void transpose_cvt(
    const float* __restrict__ W, unsigned short* __restrict__ WT, int R, int C) {
  __shared__ unsigned short t[64][66];
  const int c0 = blockIdx.x * 64, r0 = blockIdx.y * 64;
  const int tid = threadIdx.x;
  const int lr = tid >> 4;
  const int lc = (tid & 15) * 4;
#pragma unroll
  for (int p = 0; p < 4; ++p) {
    const int r = lr + p * 16;
    float4 v = *(const float4*)(W + (size_t)(r0 + r) * C + c0 + lc);
    t[r][lc + 0] = f2bf(v.x);
    t[r][lc + 1] = f2bf(v.y);
    t[r][lc + 2] = f2bf(v.z);
    t[r][lc + 3] = f2bf(v.w);
  }
  __syncthreads();
#pragma unroll
  for (int p = 0; p < 4; ++p) {
    const int oc = lr + p * 16;
    ushort4 o;
    o.x = t[lc + 0][oc];
    o.y = t[lc + 1][oc];
    o.z = t[lc + 2][oc];
    o.w = t[lc + 3][oc];
    *(ushort4*)(WT + (size_t)(c0 + oc) * R + r0 + lc) = o;
  }
}

// ---------------------------------------------------------------------------
// 256x256 8-phase bf16 GEMM. A: MxK, BT: NxK (both bf16, rows % 256 == 0,
// K % 64 == 0, K/64 >= 4). EPI 0: f32 out = acc+bias+xres; EPI 1: bf16 gelu.
// ---------------------------------------------------------------------------
template <int EPI>
__global__ __launch_bounds__(512, 2) void gemm256(
    const unsigned short* __restrict__ A, const unsigned short* __restrict__ BT,
    const float* __restrict__ bias, const float* __restrict__ xres,
    void* __restrict__ out, int N, int K) {
  __shared__ unsigned short lds[2][2][256 * 64];  // [buf][A/B][row*64+col] 128KB

  const int tid = threadIdx.x;
  const int lane = tid & 63;
  const int w = tid >> 6;        // 0..7
  const int wm = w >> 2;         // 0..1 -> rows wm*128
  const int wn = w & 3;          // 0..3 -> cols wn*64

  const int nbn = N / 256;
  const int nwg = gridDim.x;
  const int bid = blockIdx.x;
  const int wg = (bid & 7) * (nwg >> 3) + (bid >> 3);  // XCD-bijective (nwg%8==0)
  const int bm = wg / nbn, bn = wg % nbn;

  const int nt = K / 64;

  // ---- staging addressing: issue i in {0,1} covers half-local rows
  //      i*64 + w*8 + (lane>>3); phys chunk lane&7 holds logical (lane&7)^(row&7)
  const int srow = w * 8 + (lane >> 3);
  const int schunk = (lane & 7) ^ ((lane >> 3) & 7);
  const unsigned short* gA = A + (size_t)(bm * 256 + srow) * K + schunk * 8;
  const unsigned short* gB = BT + (size_t)(bn * 256 + srow) * K + schunk * 8;

  // stage one 128-row half of operand op (0=A,1=B) of K-tile `tile` into buf
  auto STAGE = [&](int buf, int op, int half, int tile) {
    const int tc = tile < nt ? tile : nt - 1;  // clamp: dead/idempotent writes
    const unsigned short* g =
        (op ? gB : gA) + (size_t)(half * 128) * K + (size_t)tc * 64;
    unsigned short* l = &lds[buf][op][(half * 128 + w * 8) * 64];
    gload_lds16(g, l);
    gload_lds16(g + (size_t)64 * K, l + 64 * 64);
  };

  // ---- fragment read addressing ----
  const int rA = wm * 128 + (lane & 15);
  const int rB = wn * 64 + (lane & 15);
  const int kq = lane >> 4;
  const int x7 = lane & 7;

  auto LDA = [&](int buf, int mh, int mf, int ks) -> bf16x8 {
    const char* p = (const char*)&lds[buf][0][0] +
                    (rA + mh * 64 + mf * 16) * 128 +
                    (((ks * 4 + kq) ^ x7) << 4);
    return *(const bf16x8*)p;
  };
  auto LDB = [&](int buf, int nh, int nf, int ks) -> bf16x8 {
    const char* p = (const char*)&lds[buf][1][0] +
                    (rB + nh * 32 + nf * 16) * 128 +
                    (((ks * 4 + kq) ^ x7) << 4);
    return *(const bf16x8*)p;
  };

  f32x4 acc[8][4] = {};
  bf16x8 aLo[4][2], aHi[4][2], bfr[2][2];

  // ---- prologue: tile0 all 4 halves + tile1 {Alo, Ahi, Blo} ----
  STAGE(0, 0, 0, 0); STAGE(0, 0, 1, 0); STAGE(0, 1, 0, 0); STAGE(0, 1, 1, 0);
  STAGE(1, 0, 0, 1); STAGE(1, 0, 1, 1); STAGE(1, 1, 0, 1);
  asm volatile("s_waitcnt vmcnt(6)" ::: "memory");  // tile0 fully landed
  __builtin_amdgcn_s_barrier();

  for (int t = 0; t < nt; ++t) {
    const int cb = t & 1, ob = cb ^ 1;
    // ======== phase 1: quadrant (mq0, nq0) — 12 ds_reads ========
#pragma unroll
    for (int mf = 0; mf < 4; ++mf)
#pragma unroll
      for (int ks = 0; ks < 2; ++ks) aLo[mf][ks] = LDA(cb, 0, mf, ks);
#pragma unroll
    for (int nf = 0; nf < 2; ++nf)
#pragma unroll
      for (int ks = 0; ks < 2; ++ks) bfr[nf][ks] = LDB(cb, 0, nf, ks);
    STAGE(ob, 1, 1, t + 1);  // B-hi(t+1) -> other buf (no conflict)
    __builtin_amdgcn_s_barrier();
    asm volatile("s_waitcnt lgkmcnt(0)" ::: "memory");
    __builtin_amdgcn_sched_barrier(0);
    __builtin_amdgcn_s_setprio(1);
#pragma unroll
    for (int mf = 0; mf < 4; ++mf)
#pragma unroll
      for (int nf = 0; nf < 2; ++nf)
#pragma unroll
        for (int ks = 0; ks < 2; ++ks)
          acc[mf][nf] = __builtin_amdgcn_mfma_f32_16x16x32_bf16(
              aLo[mf][ks], bfr[nf][ks], acc[mf][nf], 0, 0, 0);
    __builtin_amdgcn_s_setprio(0);
    __builtin_amdgcn_s_barrier();
    // ======== phase 2: quadrant (mq1, nq0) — 8 ds_reads ========
#pragma unroll
    for (int mf = 0; mf < 4; ++mf)
#pragma unroll
      for (int ks = 0; ks < 2; ++ks) aHi[mf][ks] = LDA(cb, 1, mf, ks);
    __builtin_amdgcn_s_barrier();
    asm volatile("s_waitcnt lgkmcnt(0)" ::: "memory");
    __builtin_amdgcn_sched_barrier(0);
    __builtin_amdgcn_s_setprio(1);
#pragma unroll
    for (int mf = 0; mf < 4; ++mf)
#pragma unroll
      for (int nf = 0; nf < 2; ++nf)
#pragma unroll
        for (int ks = 0; ks < 2; ++ks)
          acc[4 + mf][nf] = __builtin_amdgcn_mfma_f32_16x16x32_bf16(
              aHi[mf][ks], bfr[nf][ks], acc[4 + mf][nf], 0, 0, 0);
    __builtin_amdgcn_s_setprio(0);
    __builtin_amdgcn_s_barrier();
    // ======== phase 3: quadrant (mq1, nq1) — 4 ds_reads ========
#pragma unroll
    for (int nf = 0; nf < 2; ++nf)
#pragma unroll
      for (int ks = 0; ks < 2; ++ks) bfr[nf][ks] = LDB(cb, 1, nf, ks);
    STAGE(cb, 0, 0, t + 2);  // A-lo(t+2): A-lo reads retired at ph2 barrier
    __builtin_amdgcn_s_barrier();
    asm volatile("s_waitcnt lgkmcnt(0)" ::: "memory");
    __builtin_amdgcn_sched_barrier(0);
    __builtin_amdgcn_s_setprio(1);
#pragma unroll
    for (int mf = 0; mf < 4; ++mf)
#pragma unroll
      for (int nf = 0; nf < 2; ++nf)
#pragma unroll
        for (int ks = 0; ks < 2; ++ks)
          acc[4 + mf][2 + nf] = __builtin_amdgcn_mfma_f32_16x16x32_bf16(
              aHi[mf][ks], bfr[nf][ks], acc[4 + mf][2 + nf], 0, 0, 0);
    __builtin_amdgcn_s_setprio(0);
    __builtin_amdgcn_s_barrier();
    // ======== phase 4: quadrant (mq0, nq1) — 0 ds_reads ========
    STAGE(cb, 0, 1, t + 2);  // A-hi(t+2): A-hi reads retired at ph3 barrier
    STAGE(cb, 1, 0, t + 2);  // B-lo(t+2): B reads (ph1,ph3) retired
    __builtin_amdgcn_s_barrier();
    __builtin_amdgcn_sched_barrier(0);
    __builtin_amdgcn_s_setprio(1);
#pragma unroll
    for (int mf = 0; mf < 4; ++mf)
#pragma unroll
      for (int nf = 0; nf < 2; ++nf)
#pragma unroll
        for (int ks = 0; ks < 2; ++ks)
          acc[mf][2 + nf] = __builtin_amdgcn_mfma_f32_16x16x32_bf16(
              aLo[mf][ks], bfr[nf][ks], acc[mf][2 + nf], 0, 0, 0);
    __builtin_amdgcn_s_setprio(0);
    asm volatile("s_waitcnt vmcnt(6)" ::: "memory");  // tile t+1 fully landed
    __builtin_amdgcn_s_barrier();
  }
  asm volatile("s_waitcnt vmcnt(0)" ::: "memory");  // drain stragglers

  // ---- epilogue: C/D layout col = lane&15, row = (lane>>4)*4 + reg ----
  const int col0 = bn * 256 + wn * 64 + (lane & 15);
  const int row0 = bm * 256 + wm * 128 + ((lane >> 4) << 2);
  float bv[4];
#pragma unroll
  for (int n = 0; n < 4; ++n) bv[n] = bias[col0 + n * 16];
#pragma unroll
  for (int mf = 0; mf < 8; ++mf) {
#pragma unroll
    for (int j = 0; j < 4; ++j) {
      const size_t row = (size_t)(row0 + mf * 16 + j);
#pragma unroll
      for (int n = 0; n < 4; ++n) {
        const size_t idx = row * N + col0 + n * 16;
        float v = acc[mf][n][j] + bv[n];
        if (EPI == 0) {
          ((float*)out)[idx] = v + xres[idx];
        } else {
          float ge = 0.5f * v * (1.0f + erff(v * 0.7071067811865475f));
          ((unsigned short*)out)[idx] = f2bf(ge);
        }
      }
    }
  }
}

// ---------------------------------------------------------------------------
// Row LayerNorm over E=2048: one block per row, 8 elems/thread.
// ---------------------------------------------------------------------------
template <int OUT_BF16>
__global__ __launch_bounds__(256) void ln_row(const float* __restrict__ tin,
                                              const float* __restrict__ gw,
                                              const float* __restrict__ bw,
                                              void* __restrict__ outp) {
  const int row = blockIdx.x;
  const int tid = threadIdx.x;
  const size_t base = (size_t)row * 2048 + tid * 8;
  alignas(16) float v[8];
  *(float4*)(v) = *(const float4*)(tin + base);
  *(float4*)(v + 4) = *(const float4*)(tin + base + 4);
  float s = 0.f, q = 0.f;
#pragma unroll
  for (int i = 0; i < 8; ++i) { s += v[i]; q += v[i] * v[i]; }
#pragma unroll
  for (int m = 32; m >= 1; m >>= 1) {
    s += __shfl_xor(s, m);
    q += __shfl_xor(q, m);
  }
  __shared__ float red[8];
  if ((tid & 63) == 0) {
    red[tid >> 6] = s;
    red[4 + (tid >> 6)] = q;
  }
  __syncthreads();
  s = red[0] + red[1] + red[2] + red[3];
  q = red[4] + red[5] + red[6] + red[7];
  const float mean = s * (1.0f / 2048.0f);
  float var = q * (1.0f / 2048.0f) - mean * mean;
  var = fmaxf(var, 0.0f);
  const float rstd = rsqrtf(var + 1e-5f);
  alignas(16) float gv[8], bv[8];
  *(float4*)(gv) = *(const float4*)(gw + (size_t)tid * 8);
  *(float4*)(gv + 4) = *(const float4*)(gw + (size_t)tid * 8 + 4);
  *(float4*)(bv) = *(const float4*)(bw + (size_t)tid * 8);
  *(float4*)(bv + 4) = *(const float4*)(bw + (size_t)tid * 8 + 4);
  if (OUT_BF16) {
    ushort8 o;
#pragma unroll
    for (int i = 0; i < 8; ++i)
      o[i] = f2bf((v[i] - mean) * rstd * gv[i] + bv[i]);
    *(ushort8*)((unsigned short*)outp + base) = o;
  } else {
    alignas(16) float r[8];
#pragma unroll
    for (int i = 0; i < 8; ++i) r[i] = (v[i] - mean) * rstd * gv[i] + bv[i];
    *(float4*)((float*)outp + base) = *(float4*)(r);
    *(float4*)((float*)outp + base + 4) = *(float4*)(r + 4);
  }
}

// ---------------------------------------------------------------------------
// Launcher — workspace-size-adaptive (R2 evidence: full path, ws >= 224 MiB).
// ---------------------------------------------------------------------------
extern "C" void kernel_launch(void* const* d_in, const int* in_sizes, int n_in,
                              void* d_out, int out_size, void* d_ws,
                              size_t ws_size, hipStream_t stream) {
  constexpr int M = 8192;  // B*S
  constexpr int E = 2048;
  constexpr int F = 8192;  // 4*E
  const size_t MiB = 1ull << 20;

  const float* x = (const float*)d_in[0];
  // d_in[1] mask, d_in[2] w_attn, d_in[3] b_attn: dead (softmax over size-1)
  const float* w_kv = (const float*)d_in[4];
  const float* b_kv = (const float*)d_in[5];
  const float* ln1_g = (const float*)d_in[6];
  const float* ln1_b = (const float*)d_in[7];
  const float* w_fc = (const float*)d_in[8];
  const float* b_fc = (const float*)d_in[9];
  const float* w_mproj = (const float*)d_in[10];
  const float* b_mproj = (const float*)d_in[11];
  const float* ln2_g = (const float*)d_in[12];
  const float* ln2_b = (const float*)d_in[13];
  float* out = (float*)d_out;
  char* ws = (char*)d_ws;

  float* tbuf = out;  // t1/t2 live in d_out; in-place LN is safe

  int nch;
  unsigned short *xb, *wkvT, *wfcT, *wmpT, *hb, *gch;
  if (ws_size >= 224 * MiB) {
    nch = 1;
    gch = (unsigned short*)(ws + 0);          // 128Mi; aliases xb+wkvT (dead)
    xb = (unsigned short*)(ws + 0);
    wkvT = (unsigned short*)(ws + 32 * MiB);
    wfcT = (unsigned short*)(ws + 128 * MiB);
    wmpT = (unsigned short*)(ws + 160 * MiB);
    hb = (unsigned short*)(ws + 192 * MiB);
  } else if (ws_size >= 160 * MiB) {
    nch = 2;
    gch = (unsigned short*)(ws + 0);          // 64Mi; aliases xb+wkvT (dead)
    xb = (unsigned short*)(ws + 0);
    wkvT = (unsigned short*)(ws + 32 * MiB);
    hb = (unsigned short*)(ws + 64 * MiB);
    wfcT = (unsigned short*)(ws + 96 * MiB);
    wmpT = (unsigned short*)(ws + 128 * MiB);
  } else {
    nch = 4;
    gch = (unsigned short*)(ws + 0);          // 32Mi; aliases xb (dead)
    xb = (unsigned short*)(ws + 0);
    wkvT = (unsigned short*)(ws + 32 * MiB);  // then hb
    hb = (unsigned short*)(ws + 32 * MiB);
    wfcT = (unsigned short*)(ws + 64 * MiB);
    wmpT = (unsigned short*)(ws + 96 * MiB);
  }

  cvt_bf16_kernel<<<(M * E / 8 + 255) / 256, 256, 0, stream>>>(x, xb, M * E / 8);
  transpose_cvt<<<dim3(E / 64, E / 64), 256, 0, stream>>>(w_kv, wkvT, E, E);
  transpose_cvt<<<dim3(F / 64, E / 64), 256, 0, stream>>>(w_fc, wfcT, E, F);
  transpose_cvt<<<dim3(E / 64, F / 64), 256, 0, stream>>>(w_mproj, wmpT, F, E);

  // t1 = x @ w_kv + b_kv + x
  gemm256<0><<<(M / 256) * (E / 256), 512, 0, stream>>>(xb, wkvT, b_kv, x,
                                                        tbuf, E, E);
  // h = LN1(t1) -> bf16
  ln_row<1><<<M, 256, 0, stream>>>(tbuf, ln1_g, ln1_b, hb);
  // g = gelu(h @ w_fc + b_fc); t2 = x + g @ w_mproj + b_mproj  (M-chunked)
  const int Mc = M / nch;
  for (int c = 0; c < nch; ++c) {
    const size_t roff = (size_t)c * Mc;
    gemm256<1><<<(Mc / 256) * (F / 256), 512, 0, stream>>>(
        hb + roff * E, wfcT, b_fc, nullptr, gch, F, E);
    gemm256<0><<<(Mc / 256) * (E / 256), 512, 0, stream>>>(
        gch, wmpT, b_mproj, x + roff * E, tbuf + roff * E, E, F);
  }
  // out = LN2(t2) in place
  ln_row<0><<<M, 256, 0, stream>>>(tbuf, ln2_g, ln2_b, out);
}

// Round 5
// 689.735 us; speedup vs baseline: 1.1673x; 1.0241x over previous
//
#include <hip/hip_runtime.h>
#include <hip/hip_bf16.h>
#include <stdint.h>

// ---------------------------------------------------------------------------
// Transformer block, B=4 S=2048 E=2048 H=1.
// H=1 -> softmax over size-1 axis == 1.0 -> attn_out = x @ w_kv + b_kv.
// Pipeline: t1 = x + (x@w_kv + b_kv); h = LN1(t1);
//           g = gelu(h@w_fc + b_fc);  t2 = x + (g@w_mproj + b_mproj);
//           out = LN2(t2).
// GEMM: 256x256 tile, 8 waves (2Mx4N), BK=64, 128KB LDS dbuf, pipelined
// fragment reads (issued inside the previous MFMA window, counted lgkmcnt).
// R4 RACE FIX: each wave's 64 B^T rows lie entirely in ONE stage-half
// (wn>=2 -> B-hi), so ph4's tile-(t+1) reads need the FULL B(t+1) staged.
// New stage stream: ph3: Alo(t+2); ph4: Ahi,Blo,Bhi(t+2). Single counted
// vmcnt(2) at end-ph3 retires ALL of tile t+1 (keeps only Alo(t+2));
// prologue stages tiles 0+1 fully, vmcnt(8) retires tile 0 pre-read.
// ---------------------------------------------------------------------------

typedef __attribute__((ext_vector_type(4))) float f32x4;
typedef __attribute__((ext_vector_type(8))) __bf16 bf16x8;
typedef __attribute__((ext_vector_type(8))) unsigned short ushort8;

__device__ __forceinline__ unsigned short f2bf(float f) {
  unsigned int u = __float_as_uint(f);
  return (unsigned short)((u + 0x7FFFu + ((u >> 16) & 1u)) >> 16);  // RNE
}

__device__ __forceinline__ void gload_lds16(const void* g, void* l) {
  __builtin_amdgcn_global_load_lds(
      (const __attribute__((address_space(1))) unsigned int*)(uintptr_t)g,
      (__attribute__((address_space(3))) unsigned int*)(unsigned int)(uintptr_t)l,
      16, 0, 0);
}

#define WAITLGK(n) asm volatile("s_waitcnt lgkmcnt(" #n ")" ::: "memory")
#define WAITVM(n) asm volatile("s_waitcnt vmcnt(" #n ")" ::: "memory")
#define SBAR() __builtin_amdgcn_s_barrier()
#define SCHED0() __builtin_amdgcn_sched_barrier(0)

// ---------------------------------------------------------------------------
// f32 -> bf16 convert
// ---------------------------------------------------------------------------
__global__ __launch_bounds__(256) void cvt_bf16_kernel(
    const float* __restrict__ in, unsigned short* __restrict__ out, int n8) {
  int i = blockIdx.x * 256 + threadIdx.x;
  if (i >= n8) return;
  const size_t base = (size_t)i * 8;
  float4 a = *(const float4*)(in + base);
  float4 b = *(const float4*)(in + base + 4);
  ushort8 o;
  o[0] = f2bf(a.x); o[1] = f2bf(a.y); o[2] = f2bf(a.z); o[3] = f2bf(a.w);
  o[4] = f2bf(b.x); o[5] = f2bf(b.y); o[6] = f2bf(b.z); o[7] = f2bf(b.w);
  *(ushort8*)(out + base) = o;
}

// ---------------------------------------------------------------------------
// Transpose + convert: W (R x C f32) -> WT (C x R bf16)
// ---------------------------------------------------------------------------
__global__ __launch_bounds__(256) void transpose_cvt(
    const float* __restrict__ W, unsigned short* __restrict__ WT, int R, int C) {
  __shared__ unsigned short t[64][66];
  const int c0 = blockIdx.x * 64, r0 = blockIdx.y * 64;
  const int tid = threadIdx.x;
  const int lr = tid >> 4;
  const int lc = (tid & 15) * 4;
#pragma unroll
  for (int p = 0; p < 4; ++p) {
    const int r = lr + p * 16;
    float4 v = *(const float4*)(W + (size_t)(r0 + r) * C + c0 + lc);
    t[r][lc + 0] = f2bf(v.x);
    t[r][lc + 1] = f2bf(v.y);
    t[r][lc + 2] = f2bf(v.z);
    t[r][lc + 3] = f2bf(v.w);
  }
  __syncthreads();
#pragma unroll
  for (int p = 0; p < 4; ++p) {
    const int oc = lr + p * 16;
    ushort4 o;
    o.x = t[lc + 0][oc];
    o.y = t[lc + 1][oc];
    o.z = t[lc + 2][oc];
    o.w = t[lc + 3][oc];
    *(ushort4*)(WT + (size_t)(c0 + oc) * R + r0 + lc) = o;
  }
}

// ---------------------------------------------------------------------------
// 256x256 pipelined bf16 GEMM. A: MxK, BT: NxK (bf16, rows%256==0, K%64==0,
// K/64 >= 2). EPI 0: f32 out = acc+bias+xres; EPI 1: bf16 gelu(acc+bias).
// ---------------------------------------------------------------------------
template <int EPI>
__global__ __launch_bounds__(512, 2) void gemm256(
    const unsigned short* __restrict__ A, const unsigned short* __restrict__ BT,
    const float* __restrict__ bias, const float* __restrict__ xres,
    void* __restrict__ out, int N, int K) {
  __shared__ unsigned short lds[2][2][256 * 64];  // [buf][A/B] 128 KiB

  const int tid = threadIdx.x;
  const int lane = tid & 63;
  const int w = tid >> 6;  // 0..7
  const int wm = w >> 2;   // 0..1 -> rows wm*128
  const int wn = w & 3;    // 0..3 -> cols wn*64

  const int nbn = N / 256;
  const int nwg = gridDim.x;
  const int bid = blockIdx.x;
  const int wg = (bid & 7) * (nwg >> 3) + (bid >> 3);  // XCD-bijective (nwg%8==0)
  const int bm = wg / nbn, bn = wg % nbn;

  const int nt = K / 64;

  // ---- staging: lane covers row w*8+(lane>>3) of a 128-row half; physical
  //      16B chunk lane&7 holds logical chunk (lane&7)^(row&7) (XOR swizzle
  //      applied on the GLOBAL source; LDS dest linear).
  const int srow = w * 8 + (lane >> 3);
  const int schunk = (lane & 7) ^ ((lane >> 3) & 7);
  const unsigned short* gA = A + (size_t)(bm * 256 + srow) * K + schunk * 8;
  const unsigned short* gB = BT + (size_t)(bn * 256 + srow) * K + schunk * 8;

  // stage one 128-row half of operand op (0=A,1=B) of K-tile `tile` into buf
  auto STAGE = [&](int buf, int op, int half, int tile) {
    const int tc = tile < nt ? tile : nt - 1;  // clamp: idempotent/dead writes
    const unsigned short* g =
        (op ? gB : gA) + (size_t)(half * 128) * K + (size_t)tc * 64;
    unsigned short* l = &lds[buf][op][(half * 128 + w * 8) * 64];
    gload_lds16(g, l);
    gload_lds16(g + (size_t)64 * K, l + 64 * 64);
  };

  // ---- fragment read addressing ----
  const int rA = wm * 128 + (lane & 15);
  const int rB = wn * 64 + (lane & 15);
  const int kq = lane >> 4;
  const int x7 = lane & 7;
  const int c0 = ((kq ^ x7) << 4);        // ks=0 byte col
  const int c1 = (((4 + kq) ^ x7) << 4);  // ks=1 byte col

  f32x4 acc[8][4] = {};
  bf16x8 aS0[4][2], aS1[4][2], b0v[2][2], b1v[2][2];

#define READ_ALO(buf)                                              \
  {                                                                \
    const char* p = (const char*)&lds[buf][0][0] + rA * 128;       \
    _Pragma("unroll") for (int mf = 0; mf < 4; ++mf) {             \
      aS0[mf][0] = *(const bf16x8*)(p + mf * 2048 + c0);           \
      aS0[mf][1] = *(const bf16x8*)(p + mf * 2048 + c1);           \
    }                                                              \
  }
#define READ_AHI(buf)                                              \
  {                                                                \
    const char* p = (const char*)&lds[buf][0][0] + rA * 128 + 8192;\
    _Pragma("unroll") for (int mf = 0; mf < 4; ++mf) {             \
      aS1[mf][0] = *(const bf16x8*)(p + mf * 2048 + c0);           \
      aS1[mf][1] = *(const bf16x8*)(p + mf * 2048 + c1);           \
    }                                                              \
  }
#define READ_B0(buf)                                               \
  {                                                                \
    const char* p = (const char*)&lds[buf][1][0] + rB * 128;       \
    _Pragma("unroll") for (int nf = 0; nf < 2; ++nf) {             \
      b0v[nf][0] = *(const bf16x8*)(p + nf * 2048 + c0);           \
      b0v[nf][1] = *(const bf16x8*)(p + nf * 2048 + c1);           \
    }                                                              \
  }
#define READ_B1(buf)                                               \
  {                                                                \
    const char* p = (const char*)&lds[buf][1][0] + rB * 128 + 4096;\
    _Pragma("unroll") for (int nf = 0; nf < 2; ++nf) {             \
      b1v[nf][0] = *(const bf16x8*)(p + nf * 2048 + c0);           \
      b1v[nf][1] = *(const bf16x8*)(p + nf * 2048 + c1);           \
    }                                                              \
  }
#define CLUSTER(ASET, BSET, MO, NO)                                         \
  __builtin_amdgcn_s_setprio(1);                                            \
  _Pragma("unroll") for (int mf = 0; mf < 4; ++mf)                          \
      _Pragma("unroll") for (int nf = 0; nf < 2; ++nf)                      \
          _Pragma("unroll") for (int ks = 0; ks < 2; ++ks)                  \
              acc[MO + mf][NO + nf] =                                       \
                  __builtin_amdgcn_mfma_f32_16x16x32_bf16(                  \
                      ASET[mf][ks], BSET[nf][ks], acc[MO + mf][NO + nf],    \
                      0, 0, 0);                                             \
  __builtin_amdgcn_s_setprio(0);

  // ---- prologue: stage tiles 0 AND 1 fully (16 loads); retire tile 0
  //      (vmcnt(8)) before pre-reading aLo/b0 of tile 0.
  STAGE(0, 0, 0, 0); STAGE(0, 0, 1, 0); STAGE(0, 1, 0, 0); STAGE(0, 1, 1, 0);
  STAGE(1, 0, 0, 1); STAGE(1, 0, 1, 1); STAGE(1, 1, 0, 1); STAGE(1, 1, 1, 1);
  WAITVM(8);  // tile 0 (8 instrs) retired; tile 1 (8) in flight
  SBAR();     // group guarantee: tile 0 landed from all waves
  READ_ALO(0);
  READ_B0(0);
  // entering loop: in-flight = tile(t+1) fully = 8 instrs (steady state)

  for (int t = 0; t < nt; ++t) {
    const int cb = t & 1, ob = cb ^ 1;
    // ---- ph1: MFMA q00 (aS0 x b0); reads b1(t) ----
    READ_B1(cb);
    WAITLGK(4);  // retire aLo,b0 (issued ph4(t-1)); b1 still flying
    SCHED0();
    CLUSTER(aS0, b0v, 0, 0);
    SBAR();
    // ---- ph2: MFMA q01 (aS0 x b1); reads aHi(t) ----
    READ_AHI(cb);
    WAITLGK(8);  // retire b1; aHi still flying
    SCHED0();
    CLUSTER(aS0, b1v, 0, 2);
    SBAR();
    // ---- ph3: MFMA q10 (aS1 x b0); stage Alo(t+2); vmcnt(2) retires ALL
    //      of tile t+1 (keeps only Alo(t+2)) ----
    STAGE(cb, 0, 0, t + 2);
    WAITLGK(0);  // retire aHi
    SCHED0();
    CLUSTER(aS1, b0v, 4, 0);
    WAITVM(2);  // tile t+1 {Alo,Ahi,Blo,Bhi} fully retired
    SBAR();     // group guarantee before ph4's tile-(t+1) reads
    // ---- ph4: MFMA q11 (aS1 x b1); reads aLo,b0(t+1); stage Ahi,Blo,Bhi(t+2) ----
    READ_ALO(ob);
    READ_B0(ob);
    STAGE(cb, 0, 1, t + 2);
    STAGE(cb, 1, 0, t + 2);
    STAGE(cb, 1, 1, t + 2);
    WAITLGK(12);  // nothing older outstanding; 12 new reads fly over MFMA
    SCHED0();
    CLUSTER(aS1, b1v, 4, 2);
    SBAR();
  }
  WAITVM(0);  // drain straggler stages

  // ---- epilogue: C/D layout col = lane&15, row = (lane>>4)*4 + reg ----
  const int col0 = bn * 256 + wn * 64 + (lane & 15);
  const int row0 = bm * 256 + wm * 128 + ((lane >> 4) << 2);
  float bv[4];
#pragma unroll
  for (int n = 0; n < 4; ++n) bv[n] = bias[col0 + n * 16];
#pragma unroll
  for (int mf = 0; mf < 8; ++mf) {
#pragma unroll
    for (int j = 0; j < 4; ++j) {
      const size_t row = (size_t)(row0 + mf * 16 + j);
#pragma unroll
      for (int n = 0; n < 4; ++n) {
        const size_t idx = row * N + col0 + n * 16;
        float v = acc[mf][n][j] + bv[n];
        if (EPI == 0) {
          ((float*)out)[idx] = v + xres[idx];
        } else {
          float ge = 0.5f * v * (1.0f + erff(v * 0.7071067811865475f));
          ((unsigned short*)out)[idx] = f2bf(ge);
        }
      }
    }
  }
#undef READ_ALO
#undef READ_AHI
#undef READ_B0
#undef READ_B1
#undef CLUSTER
}

// ---------------------------------------------------------------------------
// Row LayerNorm over E=2048: one block per row, 8 elems/thread.
// ---------------------------------------------------------------------------
template <int OUT_BF16>
__global__ __launch_bounds__(256) void ln_row(const float* __restrict__ tin,
                                              const float* __restrict__ gw,
                                              const float* __restrict__ bw,
                                              void* __restrict__ outp) {
  const int row = blockIdx.x;
  const int tid = threadIdx.x;
  const size_t base = (size_t)row * 2048 + tid * 8;
  alignas(16) float v[8];
  *(float4*)(v) = *(const float4*)(tin + base);
  *(float4*)(v + 4) = *(const float4*)(tin + base + 4);
  float s = 0.f, q = 0.f;
#pragma unroll
  for (int i = 0; i < 8; ++i) { s += v[i]; q += v[i] * v[i]; }
#pragma unroll
  for (int m = 32; m >= 1; m >>= 1) {
    s += __shfl_xor(s, m);
    q += __shfl_xor(q, m);
  }
  __shared__ float red[8];
  if ((tid & 63) == 0) {
    red[tid >> 6] = s;
    red[4 + (tid >> 6)] = q;
  }
  __syncthreads();
  s = red[0] + red[1] + red[2] + red[3];
  q = red[4] + red[5] + red[6] + red[7];
  const float mean = s * (1.0f / 2048.0f);
  float var = q * (1.0f / 2048.0f) - mean * mean;
  var = fmaxf(var, 0.0f);
  const float rstd = rsqrtf(var + 1e-5f);
  alignas(16) float gv[8], bv[8];
  *(float4*)(gv) = *(const float4*)(gw + (size_t)tid * 8);
  *(float4*)(gv + 4) = *(const float4*)(gw + (size_t)tid * 8 + 4);
  *(float4*)(bv) = *(const float4*)(bw + (size_t)tid * 8);
  *(float4*)(bv + 4) = *(const float4*)(bw + (size_t)tid * 8 + 4);
  if (OUT_BF16) {
    ushort8 o;
#pragma unroll
    for (int i = 0; i < 8; ++i)
      o[i] = f2bf((v[i] - mean) * rstd * gv[i] + bv[i]);
    *(ushort8*)((unsigned short*)outp + base) = o;
  } else {
    alignas(16) float r[8];
#pragma unroll
    for (int i = 0; i < 8; ++i) r[i] = (v[i] - mean) * rstd * gv[i] + bv[i];
    *(float4*)((float*)outp + base) = *(float4*)(r);
    *(float4*)((float*)outp + base + 4) = *(float4*)(r + 4);
  }
}

// ---------------------------------------------------------------------------
// Launcher — workspace-size-adaptive (R2/R3 evidence: full path taken).
// ---------------------------------------------------------------------------
extern "C" void kernel_launch(void* const* d_in, const int* in_sizes, int n_in,
                              void* d_out, int out_size, void* d_ws,
                              size_t ws_size, hipStream_t stream) {
  constexpr int M = 8192;  // B*S
  constexpr int E = 2048;
  constexpr int F = 8192;  // 4*E
  const size_t MiB = 1ull << 20;

  const float* x = (const float*)d_in[0];
  // d_in[1] mask, d_in[2] w_attn, d_in[3] b_attn: dead (softmax over size-1)
  const float* w_kv = (const float*)d_in[4];
  const float* b_kv = (const float*)d_in[5];
  const float* ln1_g = (const float*)d_in[6];
  const float* ln1_b = (const float*)d_in[7];
  const float* w_fc = (const float*)d_in[8];
  const float* b_fc = (const float*)d_in[9];
  const float* w_mproj = (const float*)d_in[10];
  const float* b_mproj = (const float*)d_in[11];
  const float* ln2_g = (const float*)d_in[12];
  const float* ln2_b = (const float*)d_in[13];
  float* out = (float*)d_out;
  char* ws = (char*)d_ws;

  float* tbuf = out;  // t1/t2 live in d_out; in-place LN is safe

  int nch;
  unsigned short *xb, *wkvT, *wfcT, *wmpT, *hb, *gch;
  if (ws_size >= 224 * MiB) {
    nch = 1;
    gch = (unsigned short*)(ws + 0);  // 128Mi; aliases xb+wkvT (dead by then)
    xb = (unsigned short*)(ws + 0);
    wkvT = (unsigned short*)(ws + 32 * MiB);
    wfcT = (unsigned short*)(ws + 128 * MiB);
    wmpT = (unsigned short*)(ws + 160 * MiB);
    hb = (unsigned short*)(ws + 192 * MiB);
  } else if (ws_size >= 160 * MiB) {
    nch = 2;
    gch = (unsigned short*)(ws + 0);
    xb = (unsigned short*)(ws + 0);
    wkvT = (unsigned short*)(ws + 32 * MiB);
    hb = (unsigned short*)(ws + 64 * MiB);
    wfcT = (unsigned short*)(ws + 96 * MiB);
    wmpT = (unsigned short*)(ws + 128 * MiB);
  } else {
    nch = 4;
    gch = (unsigned short*)(ws + 0);
    xb = (unsigned short*)(ws + 0);
    wkvT = (unsigned short*)(ws + 32 * MiB);
    hb = (unsigned short*)(ws + 32 * MiB);
    wfcT = (unsigned short*)(ws + 64 * MiB);
    wmpT = (unsigned short*)(ws + 96 * MiB);
  }

  cvt_bf16_kernel<<<(M * E / 8 + 255) / 256, 256, 0, stream>>>(x, xb, M * E / 8);
  transpose_cvt<<<dim3(E / 64, E / 64), 256, 0, stream>>>(w_kv, wkvT, E, E);
  transpose_cvt<<<dim3(F / 64, E / 64), 256, 0, stream>>>(w_fc, wfcT, E, F);
  transpose_cvt<<<dim3(E / 64, F / 64), 256, 0, stream>>>(w_mproj, wmpT, F, E);

  // t1 = x @ w_kv + b_kv + x
  gemm256<0><<<(M / 256) * (E / 256), 512, 0, stream>>>(xb, wkvT, b_kv, x,
                                                        tbuf, E, E);
  // h = LN1(t1) -> bf16
  ln_row<1><<<M, 256, 0, stream>>>(tbuf, ln1_g, ln1_b, hb);
  // g = gelu(h @ w_fc + b_fc); t2 = x + g @ w_mproj + b_mproj  (M-chunked)
  const int Mc = M / nch;
  for (int c = 0; c < nch; ++c) {
    const size_t roff = (size_t)c * Mc;
    gemm256<1><<<(Mc / 256) * (F / 256), 512, 0, stream>>>(
        hb + roff * E, wfcT, b_fc, nullptr, gch, F, E);
    gemm256<0><<<(Mc / 256) * (E / 256), 512, 0, stream>>>(
        gch, wmpT, b_mproj, x + roff * E, tbuf + roff * E, E, F);
  }
  // out = LN2(t2) in place
  ln_row<0><<<M, 256, 0, stream>>>(tbuf, ln2_g, ln2_b, out);
}

// Round 6
// 686.809 us; speedup vs baseline: 1.1723x; 1.0043x over previous
//
#include <hip/hip_runtime.h>
#include <hip/hip_bf16.h>
#include <stdint.h>

// ---------------------------------------------------------------------------
// Transformer block, B=4 S=2048 E=2048 H=1.
// H=1 -> softmax over size-1 axis == 1.0 -> attn_out = x @ w_kv + b_kv.
// Pipeline: t1 = x + (x@w_kv + b_kv); h = LN1(t1);
//           g = gelu(h@w_fc + b_fc);  t2 = x + (g@w_mproj + b_mproj);
//           out = LN2(t2).
// GEMM: 256x256 tile, 8 waves (2Mx4N), BK=64, 128KB LDS dbuf, 8-phase
// schedule with PHASE-ALIGNED LDS regions: A-region h = rows with mh=h for
// BOTH wm strips ({0-63}u{128-191} for h=0), B-region h = nh=h rows. Region
// read-lifetime is 1-2 phases -> stage exactly 1 half-tile (2 gloads) per
// phase, counted vmcnt(6)/(8) (never 0), reads-for-own-phase with
// lgkmcnt(0) after the barrier. 2 K-tiles per iteration, static buffer
// indices. (R3/R5 used row-ordered halves: every wave read every region
// every phase -> staging bunched into ph3/ph4 colliding with reads, and
// full-tile vmcnt retirement exposed HBM latency -> serial ~6000 cyc/tile.)
// ---------------------------------------------------------------------------

typedef __attribute__((ext_vector_type(4))) float f32x4;
typedef __attribute__((ext_vector_type(8))) __bf16 bf16x8;
typedef __attribute__((ext_vector_type(8))) unsigned short ushort8;

__device__ __forceinline__ unsigned short f2bf(float f) {
  unsigned int u = __float_as_uint(f);
  return (unsigned short)((u + 0x7FFFu + ((u >> 16) & 1u)) >> 16);  // RNE
}

__device__ __forceinline__ void gload_lds16(const void* g, void* l) {
  __builtin_amdgcn_global_load_lds(
      (const __attribute__((address_space(1))) unsigned int*)(uintptr_t)g,
      (__attribute__((address_space(3))) unsigned int*)(unsigned int)(uintptr_t)l,
      16, 0, 0);
}

#define WAITLGK(n) asm volatile("s_waitcnt lgkmcnt(" #n ")" ::: "memory")
#define WAITVM(n) asm volatile("s_waitcnt vmcnt(" #n ")" ::: "memory")
#define SBAR() __builtin_amdgcn_s_barrier()

// ---------------------------------------------------------------------------
// f32 -> bf16 convert
// ---------------------------------------------------------------------------
__global__ __launch_bounds__(256) void cvt_bf16_kernel(
    const float* __restrict__ in, unsigned short* __restrict__ out, int n8) {
  int i = blockIdx.x * 256 + threadIdx.x;
  if (i >= n8) return;
  const size_t base = (size_t)i * 8;
  float4 a = *(const float4*)(in + base);
  float4 b = *(const float4*)(in + base + 4);
  ushort8 o;
  o[0] = f2bf(a.x); o[1] = f2bf(a.y); o[2] = f2bf(a.z); o[3] = f2bf(a.w);
  o[4] = f2bf(b.x); o[5] = f2bf(b.y); o[6] = f2bf(b.z); o[7] = f2bf(b.w);
  *(ushort8*)(out + base) = o;
}

// ---------------------------------------------------------------------------
// Transpose + convert: W (R x C f32) -> WT (C x R bf16)
// ---------------------------------------------------------------------------
__global__ __launch_bounds__(256) void transpose_cvt(
    const float* __restrict__ W, unsigned short* __restrict__ WT, int R, int C) {
  __shared__ unsigned short t[64][66];
  const int c0 = blockIdx.x * 64, r0 = blockIdx.y * 64;
  const int tid = threadIdx.x;
  const int lr = tid >> 4;
  const int lc = (tid & 15) * 4;
#pragma unroll
  for (int p = 0; p < 4; ++p) {
    const int r = lr + p * 16;
    float4 v = *(const float4*)(W + (size_t)(r0 + r) * C + c0 + lc);
    t[r][lc + 0] = f2bf(v.x);
    t[r][lc + 1] = f2bf(v.y);
    t[r][lc + 2] = f2bf(v.z);
    t[r][lc + 3] = f2bf(v.w);
  }
  __syncthreads();
#pragma unroll
  for (int p = 0; p < 4; ++p) {
    const int oc = lr + p * 16;
    ushort4 o;
    o.x = t[lc + 0][oc];
    o.y = t[lc + 1][oc];
    o.z = t[lc + 2][oc];
    o.w = t[lc + 3][oc];
    *(ushort4*)(WT + (size_t)(c0 + oc) * R + r0 + lc) = o;
  }
}

// ---------------------------------------------------------------------------
// 256x256 8-phase bf16 GEMM, phase-aligned LDS regions.
// A: MxK, BT: NxK (bf16, rows%256==0, K%128==0).
// EPI 0: f32 out = acc+bias+xres; EPI 1: bf16 gelu(acc+bias).
// ---------------------------------------------------------------------------
template <int EPI>
__global__ __launch_bounds__(512, 2) void gemm256(
    const unsigned short* __restrict__ A, const unsigned short* __restrict__ BT,
    const float* __restrict__ bias, const float* __restrict__ xres,
    void* __restrict__ out, int N, int K) {
  // L[buf][op][region][128*64] ; each region 16 KiB; total 128 KiB.
  __shared__ unsigned short L[2][2][2][8192];

  const int tid = threadIdx.x;
  const int lane = tid & 63;
  const int w = tid >> 6;  // 0..7
  const int wm = w >> 2;   // 0..1 -> rows wm*128
  const int wn = w & 3;    // 0..3 -> cols wn*64
  const int l15 = lane & 15;

  const int nbn = N / 256;
  const int nwg = gridDim.x;
  const int bid = blockIdx.x;
  const int wg = (bid & 7) * (nwg >> 3) + (bid >> 3);  // XCD-bijective (nwg%8==0)
  const int bm = wg / nbn, bn = wg % nbn;

  const int nt = K / 64;  // even

  // ---- staging lane addressing: lane covers region-row rr = w*8+(lane>>3)
  //      (+64 for the second gload); physical chunk lane&7 holds logical
  //      chunk (lane&7)^(rr&7) (XOR swizzle on the GLOBAL source).
  const int srow = w * 8 + (lane >> 3);
  const int schunk = (lane & 7) ^ ((lane >> 3) & 7);
  // global rows: A region h row rr -> bm*256 + (rr>>6)*128 + h*64 + (rr&63)
  //              B region h row rr -> bn*256 + (rr>>5)*64  + h*32 + (rr&31)
  const unsigned short* pb[2][2][2];  // [op][h][j]  (j = rr/64)
#pragma unroll
  for (int h = 0; h < 2; ++h)
#pragma unroll
    for (int j = 0; j < 2; ++j) {
      pb[0][h][j] =
          A + (size_t)(bm * 256 + j * 128 + h * 64 + srow) * K + schunk * 8;
      pb[1][h][j] = BT +
                    (size_t)(bn * 256 + ((srow >> 5) + 2 * j) * 64 + h * 32 +
                             (srow & 31)) * K +
                    schunk * 8;
    }

#define STAGE(BUF, OP, H, TILE)                                            \
  {                                                                        \
    const size_t ko_ = (size_t)(TILE) * 64;                                \
    gload_lds16(pb[OP][H][0] + ko_, &L[BUF][OP][H][w * 512]);              \
    gload_lds16(pb[OP][H][1] + ko_, &L[BUF][OP][H][w * 512 + 4096]);       \
  }

  // ---- fragment read addressing ----
  const int kq = lane >> 4;
  const int x7 = lane & 7;
  const int cc0 = ((kq ^ x7) << 4);        // ks=0 byte col
  const int cc1 = (((4 + kq) ^ x7) << 4);  // ks=1 byte col
  const int rAoff = (wm * 64 + l15) * 128;  // region-row byte base (A)
  const int rBoff = (wn * 32 + l15) * 128;  // region-row byte base (B)

  f32x4 acc[8][4] = {};
  bf16x8 aF[4][2], b0F[2][2], b1F[2][2];

#define RD_A(BUF, H)                                                   \
  {                                                                    \
    const char* p_ = (const char*)&L[BUF][0][H][0] + rAoff;            \
    _Pragma("unroll") for (int mf = 0; mf < 4; ++mf) {                 \
      aF[mf][0] = *(const bf16x8*)(p_ + mf * 2048 + cc0);              \
      aF[mf][1] = *(const bf16x8*)(p_ + mf * 2048 + cc1);              \
    }                                                                  \
  }
#define RD_B(BUF, H, DST)                                              \
  {                                                                    \
    const char* p_ = (const char*)&L[BUF][1][H][0] + rBoff;            \
    _Pragma("unroll") for (int nf = 0; nf < 2; ++nf) {                 \
      DST[nf][0] = *(const bf16x8*)(p_ + nf * 2048 + cc0);             \
      DST[nf][1] = *(const bf16x8*)(p_ + nf * 2048 + cc1);             \
    }                                                                  \
  }
#define CLUSTER(BSET, MO, NO)                                               \
  __builtin_amdgcn_s_setprio(1);                                            \
  _Pragma("unroll") for (int mf = 0; mf < 4; ++mf)                          \
      _Pragma("unroll") for (int nf = 0; nf < 2; ++nf)                      \
          _Pragma("unroll") for (int ks = 0; ks < 2; ++ks)                  \
              acc[MO + mf][NO + nf] =                                       \
                  __builtin_amdgcn_mfma_f32_16x16x32_bf16(                  \
                      aF[mf][ks], BSET[nf][ks], acc[MO + mf][NO + nf],      \
                      0, 0, 0);                                             \
  __builtin_amdgcn_s_setprio(0);

  // ---- prologue: 6 stages in steady-state FIFO order, retire tile-0 A0,B0.
  STAGE(0, 0, 0, 0);  // A0(0)
  STAGE(0, 1, 0, 0);  // B0(0)
  STAGE(0, 0, 1, 0);  // A1(0)
  STAGE(0, 1, 1, 0);  // B1(0)
  STAGE(1, 0, 0, 1);  // A0(1)
  STAGE(1, 1, 0, 1);  // B0(1)
  WAITVM(8);          // A0(0),B0(0) landed; 8 instr in flight
  SBAR();

  for (int t2 = 0; t2 < nt; t2 += 2) {
    const int tn2 = (t2 + 2 < nt) ? t2 + 2 : nt - 1;  // clamped lookahead
    const int tn3 = (t2 + 3 < nt) ? t2 + 3 : nt - 1;
    // ---- ph1: q00(buf0); reads A0+B0; stage A1(t2+1)->buf1 ----
    RD_A(0, 0); RD_B(0, 0, b0F);
    STAGE(1, 0, 1, t2 + 1);
    WAITLGK(8);
    SBAR(); WAITLGK(0);
    CLUSTER(b0F, 0, 0);
    WAITVM(6);  // retire A1(t2),B1(t2): ph2/ph3 read them
    SBAR();
    // ---- ph2: q01(buf0); reads B1; stage B1(t2+1)->buf1 ----
    RD_B(0, 1, b1F);
    STAGE(1, 1, 1, t2 + 1);
    SBAR(); WAITLGK(0);
    CLUSTER(b1F, 0, 2);
    SBAR();
    // ---- ph3: q10(buf0); reads A1; stage A0(t2+2)->buf0 ----
    RD_A(0, 1);
    STAGE(0, 0, 0, tn2);
    SBAR(); WAITLGK(0);
    CLUSTER(b0F, 4, 0);
    SBAR();
    // ---- ph4: q11(buf0); stage B0(t2+2)->buf0 ----
    STAGE(0, 1, 0, tn2);
    SBAR();
    CLUSTER(b1F, 4, 2);
    WAITVM(8);  // retire A0(t2+1),B0(t2+1): ph5 reads them
    SBAR();
    // ---- ph5: q00(buf1); reads A0+B0; stage A1(t2+2)->buf0 ----
    RD_A(1, 0); RD_B(1, 0, b0F);
    STAGE(0, 0, 1, tn2);
    WAITLGK(8);
    SBAR(); WAITLGK(0);
    CLUSTER(b0F, 0, 0);
    WAITVM(6);  // retire A1(t2+1),B1(t2+1): ph6/ph7 read them
    SBAR();
    // ---- ph6: q01(buf1); reads B1; stage B1(t2+2)->buf0 ----
    RD_B(1, 1, b1F);
    STAGE(0, 1, 1, tn2);
    SBAR(); WAITLGK(0);
    CLUSTER(b1F, 0, 2);
    SBAR();
    // ---- ph7: q10(buf1); reads A1; stage A0(t2+3)->buf1 ----
    RD_A(1, 1);
    STAGE(1, 0, 0, tn3);
    SBAR(); WAITLGK(0);
    CLUSTER(b0F, 4, 0);
    SBAR();
    // ---- ph8: q11(buf1); stage B0(t2+3)->buf1 ----
    STAGE(1, 1, 0, tn3);
    SBAR();
    CLUSTER(b1F, 4, 2);
    WAITVM(8);  // retire A0(t2+2),B0(t2+2): next ph1 reads them
    SBAR();
  }
  WAITVM(0);  // drain straggler stages

  // ---- epilogue: C/D layout col = lane&15, row = (lane>>4)*4 + reg ----
  const int col0 = bn * 256 + wn * 64 + l15;
  const int row0 = bm * 256 + wm * 128 + ((lane >> 4) << 2);
  float bv[4];
#pragma unroll
  for (int n = 0; n < 4; ++n) bv[n] = bias[col0 + n * 16];
#pragma unroll
  for (int mf = 0; mf < 8; ++mf) {
#pragma unroll
    for (int j = 0; j < 4; ++j) {
      const size_t row = (size_t)(row0 + mf * 16 + j);
#pragma unroll
      for (int n = 0; n < 4; ++n) {
        const size_t idx = row * N + col0 + n * 16;
        float v = acc[mf][n][j] + bv[n];
        if (EPI == 0) {
          ((float*)out)[idx] = v + xres[idx];
        } else {
          float ge = 0.5f * v * (1.0f + erff(v * 0.7071067811865475f));
          ((unsigned short*)out)[idx] = f2bf(ge);
        }
      }
    }
  }
#undef RD_A
#undef RD_B
#undef CLUSTER
#undef STAGE
}

// ---------------------------------------------------------------------------
// Row LayerNorm over E=2048: one block per row, 8 elems/thread.
// ---------------------------------------------------------------------------
template <int OUT_BF16>
__global__ __launch_bounds__(256) void ln_row(const float* __restrict__ tin,
                                              const float* __restrict__ gw,
                                              const float* __restrict__ bw,
                                              void* __restrict__ outp) {
  const int row = blockIdx.x;
  const int tid = threadIdx.x;
  const size_t base = (size_t)row * 2048 + tid * 8;
  alignas(16) float v[8];
  *(float4*)(v) = *(const float4*)(tin + base);
  *(float4*)(v + 4) = *(const float4*)(tin + base + 4);
  float s = 0.f, q = 0.f;
#pragma unroll
  for (int i = 0; i < 8; ++i) { s += v[i]; q += v[i] * v[i]; }
#pragma unroll
  for (int m = 32; m >= 1; m >>= 1) {
    s += __shfl_xor(s, m);
    q += __shfl_xor(q, m);
  }
  __shared__ float red[8];
  if ((tid & 63) == 0) {
    red[tid >> 6] = s;
    red[4 + (tid >> 6)] = q;
  }
  __syncthreads();
  s = red[0] + red[1] + red[2] + red[3];
  q = red[4] + red[5] + red[6] + red[7];
  const float mean = s * (1.0f / 2048.0f);
  float var = q * (1.0f / 2048.0f) - mean * mean;
  var = fmaxf(var, 0.0f);
  const float rstd = rsqrtf(var + 1e-5f);
  alignas(16) float gv[8], bv[8];
  *(float4*)(gv) = *(const float4*)(gw + (size_t)tid * 8);
  *(float4*)(gv + 4) = *(const float4*)(gw + (size_t)tid * 8 + 4);
  *(float4*)(bv) = *(const float4*)(bw + (size_t)tid * 8);
  *(float4*)(bv + 4) = *(const float4*)(bw + (size_t)tid * 8 + 4);
  if (OUT_BF16) {
    ushort8 o;
#pragma unroll
    for (int i = 0; i < 8; ++i)
      o[i] = f2bf((v[i] - mean) * rstd * gv[i] + bv[i]);
    *(ushort8*)((unsigned short*)outp + base) = o;
  } else {
    alignas(16) float r[8];
#pragma unroll
    for (int i = 0; i < 8; ++i) r[i] = (v[i] - mean) * rstd * gv[i] + bv[i];
    *(float4*)((float*)outp + base) = *(float4*)(r);
    *(float4*)((float*)outp + base + 4) = *(float4*)(r + 4);
  }
}

// ---------------------------------------------------------------------------
// Launcher — workspace-size-adaptive (R2/R3 evidence: full path taken).
// ---------------------------------------------------------------------------
extern "C" void kernel_launch(void* const* d_in, const int* in_sizes, int n_in,
                              void* d_out, int out_size, void* d_ws,
                              size_t ws_size, hipStream_t stream) {
  constexpr int M = 8192;  // B*S
  constexpr int E = 2048;
  constexpr int F = 8192;  // 4*E
  const size_t MiB = 1ull << 20;

  const float* x = (const float*)d_in[0];
  // d_in[1] mask, d_in[2] w_attn, d_in[3] b_attn: dead (softmax over size-1)
  const float* w_kv = (const float*)d_in[4];
  const float* b_kv = (const float*)d_in[5];
  const float* ln1_g = (const float*)d_in[6];
  const float* ln1_b = (const float*)d_in[7];
  const float* w_fc = (const float*)d_in[8];
  const float* b_fc = (const float*)d_in[9];
  const float* w_mproj = (const float*)d_in[10];
  const float* b_mproj = (const float*)d_in[11];
  const float* ln2_g = (const float*)d_in[12];
  const float* ln2_b = (const float*)d_in[13];
  float* out = (float*)d_out;
  char* ws = (char*)d_ws;

  float* tbuf = out;  // t1/t2 live in d_out; in-place LN is safe

  int nch;
  unsigned short *xb, *wkvT, *wfcT, *wmpT, *hb, *gch;
  if (ws_size >= 224 * MiB) {
    nch = 1;
    gch = (unsigned short*)(ws + 0);  // 128Mi; aliases xb+wkvT (dead by then)
    xb = (unsigned short*)(ws + 0);
    wkvT = (unsigned short*)(ws + 32 * MiB);
    wfcT = (unsigned short*)(ws + 128 * MiB);
    wmpT = (unsigned short*)(ws + 160 * MiB);
    hb = (unsigned short*)(ws + 192 * MiB);
  } else if (ws_size >= 160 * MiB) {
    nch = 2;
    gch = (unsigned short*)(ws + 0);
    xb = (unsigned short*)(ws + 0);
    wkvT = (unsigned short*)(ws + 32 * MiB);
    hb = (unsigned short*)(ws + 64 * MiB);
    wfcT = (unsigned short*)(ws + 96 * MiB);
    wmpT = (unsigned short*)(ws + 128 * MiB);
  } else {
    nch = 4;
    gch = (unsigned short*)(ws + 0);
    xb = (unsigned short*)(ws + 0);
    wkvT = (unsigned short*)(ws + 32 * MiB);
    hb = (unsigned short*)(ws + 32 * MiB);
    wfcT = (unsigned short*)(ws + 64 * MiB);
    wmpT = (unsigned short*)(ws + 96 * MiB);
  }

  cvt_bf16_kernel<<<(M * E / 8 + 255) / 256, 256, 0, stream>>>(x, xb, M * E / 8);
  transpose_cvt<<<dim3(E / 64, E / 64), 256, 0, stream>>>(w_kv, wkvT, E, E);
  transpose_cvt<<<dim3(F / 64, E / 64), 256, 0, stream>>>(w_fc, wfcT, E, F);
  transpose_cvt<<<dim3(E / 64, F / 64), 256, 0, stream>>>(w_mproj, wmpT, F, E);

  // t1 = x @ w_kv + b_kv + x
  gemm256<0><<<(M / 256) * (E / 256), 512, 0, stream>>>(xb, wkvT, b_kv, x,
                                                        tbuf, E, E);
  // h = LN1(t1) -> bf16
  ln_row<1><<<M, 256, 0, stream>>>(tbuf, ln1_g, ln1_b, hb);
  // g = gelu(h @ w_fc + b_fc); t2 = x + g @ w_mproj + b_mproj  (M-chunked)
  const int Mc = M / nch;
  for (int c = 0; c < nch; ++c) {
    const size_t roff = (size_t)c * Mc;
    gemm256<1><<<(Mc / 256) * (F / 256), 512, 0, stream>>>(
        hb + roff * E, wfcT, b_fc, nullptr, gch, F, E);
    gemm256<0><<<(Mc / 256) * (E / 256), 512, 0, stream>>>(
        gch, wmpT, b_mproj, x + roff * E, tbuf + roff * E, E, F);
  }
  // out = LN2(t2) in place
  ln_row<0><<<M, 256, 0, stream>>>(tbuf, ln2_g, ln2_b, out);
}